// Round 10
// baseline (176.052 us; speedup 1.0000x reference)
//
#include <hip/hip_runtime.h>

#define LRELU_ALPHA 0.2f

typedef __bf16 bf16x8 __attribute__((ext_vector_type(8)));
typedef unsigned short u16;
typedef unsigned short u16x8 __attribute__((ext_vector_type(8)));
typedef float f32x4 __attribute__((ext_vector_type(4)));
typedef int int4v __attribute__((ext_vector_type(4)));
typedef unsigned int u32;
typedef unsigned int u32x4 __attribute__((ext_vector_type(4)));
typedef unsigned long long u64;

__device__ __forceinline__ u16 f2bf(float f) {
  unsigned int u = __float_as_uint(f);
  u += 0x7fffu + ((u >> 16) & 1u);   // RNE
  return (u16)(u >> 16);
}

// ------- kernel 1: packadj (blocks 0..4095) + wcast (blocks 4096..4351) ----
__global__ __launch_bounds__(256) void packw(const int* __restrict__ adj,
                                             u32* __restrict__ maskg,
                                             const float* __restrict__ W,
                                             u16* __restrict__ WbT) {
  const int tid = threadIdx.x;
  if (blockIdx.x >= 4096) {
    int idx = (blockIdx.x - 4096) * 256 + tid;        // 65536
    WbT[idx] = f2bf(W[(idx & 255) * 256 + (idx >> 8)]);
    return;
  }
  const int l = tid & 63, w = tid >> 6;
  const size_t row = (size_t)blockIdx.x * 4 + w;
  const int* arow = adj + row * 4096;
  u64* mrow = (u64*)(maskg + row * 128);
  for (int it = 0; it < 16; ++it) {
    const int* base = arow + it * 256;
    int v0 = base[l], v1 = base[l + 64], v2 = base[l + 128], v3 = base[l + 192];
    u64 b0 = __ballot(v0 != 0);
    u64 b1 = __ballot(v1 != 0);
    u64 b2 = __ballot(v2 != 0);
    u64 b3 = __ballot(v3 != 0);
    if (l == 0) {
      mrow[it * 4 + 0] = b0;
      mrow[it * 4 + 1] = b1;
      mrow[it * 4 + 2] = b2;
      mrow[it * 4 + 3] = b3;
    }
  }
}

// ---------------- kernel 2: Hh = bf16(h) @ W, fused s/d dots ----------
// HhTt tiled layout (u16 index):
// b*1048576 + (k>>5)*8192 + (col>>4)*512 + ((k>>3)&3)*128 + (col&15)*8 + (k&7)
__global__ __launch_bounds__(256) void gemm1(const float* __restrict__ h,
                                             const u16* __restrict__ WbT,
                                             const float* __restrict__ a,
                                             u16* __restrict__ HhTt,
                                             float* __restrict__ sbuf,
                                             float* __restrict__ dbuf) {
  const int tid = threadIdx.x, bid = blockIdx.x;
  const int l = tid & 63, w = tid >> 6;
  const int lr = l & 15;
  const int lk = (l >> 4) << 3;
  const int rowA = bid * 64 + 16 * w + lr;
  const float* hrow = h + (size_t)rowA * 256 + lk;

  f32x4 acc[16];
#pragma unroll
  for (int n = 0; n < 16; ++n) acc[n] = (f32x4){0.f, 0.f, 0.f, 0.f};

  for (int k0 = 0; k0 < 256; k0 += 32) {
    f32x4 a0 = *(const f32x4*)(hrow + k0);
    f32x4 a1 = *(const f32x4*)(hrow + k0 + 4);
    u16x8 au;
    au[0] = f2bf(a0[0]); au[1] = f2bf(a0[1]); au[2] = f2bf(a0[2]); au[3] = f2bf(a0[3]);
    au[4] = f2bf(a1[0]); au[5] = f2bf(a1[1]); au[6] = f2bf(a1[2]); au[7] = f2bf(a1[3]);
    bf16x8 af = __builtin_bit_cast(bf16x8, au);
#pragma unroll
    for (int n = 0; n < 16; ++n) {
      int4v bv = *(const int4v*)(WbT + (size_t)(16 * n + lr) * 256 + k0 + lk);
      bf16x8 bf = __builtin_bit_cast(bf16x8, bv);
      acc[n] = __builtin_amdgcn_mfma_f32_16x16x32_bf16(af, bf, acc[n], 0, 0, 0);
    }
  }

  float sp[4] = {0.f, 0.f, 0.f, 0.f}, dp[4] = {0.f, 0.f, 0.f, 0.f};
#pragma unroll
  for (int n = 0; n < 16; ++n) {
    int col = 16 * n + lr;
    float as = a[col];
    float ad = a[256 + col];
#pragma unroll
    for (int rr = 0; rr < 4; ++rr) {
      int row = bid * 64 + 16 * w + ((l >> 4) << 2) + rr;
      int bb = row >> 12, kk = row & 4095;
      float v = acc[n][rr];
      size_t addr = (size_t)bb * 1048576 + (size_t)(kk >> 5) * 8192 +
                    (col >> 4) * 512 + ((kk >> 3) & 3) * 128 + (col & 15) * 8 +
                    (kk & 7);
      HhTt[addr] = f2bf(v);
      sp[rr] += v * as;
      dp[rr] += v * ad;
    }
  }
#pragma unroll
  for (int rr = 0; rr < 4; ++rr) {
#pragma unroll
    for (int off = 1; off < 16; off <<= 1) {
      sp[rr] += __shfl_xor(sp[rr], off);
      dp[rr] += __shfl_xor(dp[rr], off);
    }
  }
  if ((l & 15) == 0) {
#pragma unroll
    for (int rr = 0; rr < 4; ++rr) {
      int row = bid * 64 + 16 * w + ((l >> 4) << 2) + rr;
      sbuf[row] = sp[rr];
      dbuf[row] = dp[rr];
    }
  }
}

// ---------------- kernel 3: main fused GAT aggregation ----------------
// grid 512, 512 thr / 8 waves, launch_bounds(512,4) -> 2 blocks/CU =
// 16 waves/CU. BM=64 rows x BN=128 cols per block (col-split ch).
// Barrier-free K-loop: e in registers from LDS mask+d, B direct from
// L2-resident HhTt; depth-1 double-buffered register prefetch (A/B sets).
__global__ __launch_bounds__(512, 4) void gat_main(const u32* __restrict__ maskg,
                                                   const u16* __restrict__ HhTt,
                                                   const float* __restrict__ s,
                                                   const float* __restrict__ d,
                                                   float* __restrict__ out) {
  __shared__ __align__(16) u32 Mk[64 * 128];   // 32 KB rotated mask panel
  __shared__ __align__(16) float Dl[4096];     // 16 KB

  const int tid = threadIdx.x, bid = blockIdx.x;
  const int xcd = bid & 7;
  const int t = (xcd << 6) | (bid >> 3);       // 0..511 bijective
  const int b = t >> 7;                        // batch -> XCD pair
  const int loc = t & 127;
  const int rowbase = (loc >> 1) << 6;
  const int ch = loc & 1;                      // column half

  const int l = tid & 63, w = tid >> 6;        // w 0..7
  const int lr = l & 15, lkg = l >> 4;
  const int wr = w & 3, wc = w >> 2;           // 4 row-quads x 2 col-halves
  const int rowl = wr * 16 + lr;               // local row 0..63

  // ---- prologue: stage d (16KB) + rotated 64-row mask panel (32KB) ----
  for (int i = tid; i < 1024; i += 512)
    *(f32x4*)&Dl[i * 4] = *(const f32x4*)(d + b * 4096 + i * 4);
  {
    const u32* mrow = maskg + ((size_t)(b * 4096 + rowbase)) * 128;
    const int r = tid >> 3, c0 = (tid & 7) * 16;
#pragma unroll
    for (int j = 0; j < 16; ++j) {
      int c = c0 + j;
      Mk[r * 128 + ((c + r) & 127)] = mrow[r * 128 + c];
    }
  }
  const float s_row = s[b * 4096 + rowbase + rowl];
  __syncthreads();   // the only block-wide barrier

  // B source: tiled layout; this lane's 16B chunk of col-group (ch*8+wc*4+n)
  const char* bsrc = (const char*)HhTt +
      ((size_t)b * 1048576 + (size_t)(ch * 8 + wc * 4) * 512 + lkg * 128 + lr * 8) * 2;

  f32x4 acc[4];
#pragma unroll
  for (int n = 0; n < 4; ++n) acc[n] = (f32x4){0.f, 0.f, 0.f, 0.f};
  float racc = 0.f;
  const int mkbase = rowl * 128;

  // A/B register sets for depth-1 prefetch (static names per rule 20)
  int4v bvA0, bvA1, bvA2, bvA3, bvB0, bvB1, bvB2, bvB3;
  u32 mwA, mwB;
  f32x4 dA0, dA1, dB0, dB1;

#define LOADSTEP(S, STEP)                                                     \
  {                                                                           \
    const int st_ = (STEP) & 127;                                             \
    const char* bs_ = bsrc + (size_t)st_ * 16384;                             \
    bv##S##0 = *(const int4v*)(bs_);                                          \
    bv##S##1 = *(const int4v*)(bs_ + 1024);                                   \
    bv##S##2 = *(const int4v*)(bs_ + 2048);                                   \
    bv##S##3 = *(const int4v*)(bs_ + 3072);                                   \
    mw##S = Mk[mkbase + ((st_ + rowl) & 127)];                                \
    d##S##0 = *(const f32x4*)&Dl[st_ * 32 + lkg * 8];                         \
    d##S##1 = *(const f32x4*)&Dl[st_ * 32 + lkg * 8 + 4];                     \
  }

#define COMP(S)                                                               \
  {                                                                           \
    u32 m8 = mw##S >> (lkg * 8);                                              \
    float ev[8];                                                              \
    _Pragma("unroll")                                                         \
    for (int j = 0; j < 8; ++j) {                                             \
      float lg = s_row + (j < 4 ? d##S##0[j & 3] : d##S##1[j & 3]);           \
      float tt = fmaxf(lg, LRELU_ALPHA * lg);                                 \
      float e = ((m8 >> j) & 1) ? __expf(-tt) : 0.f;                          \
      racc += e;                                                              \
      ev[j] = e;                                                              \
    }                                                                         \
    u32x4 pk;                                                                 \
    asm("v_cvt_pk_bf16_f32 %0, %1, %2" : "=v"(pk[0]) : "v"(ev[0]), "v"(ev[1])); \
    asm("v_cvt_pk_bf16_f32 %0, %1, %2" : "=v"(pk[1]) : "v"(ev[2]), "v"(ev[3])); \
    asm("v_cvt_pk_bf16_f32 %0, %1, %2" : "=v"(pk[2]) : "v"(ev[4]), "v"(ev[5])); \
    asm("v_cvt_pk_bf16_f32 %0, %1, %2" : "=v"(pk[3]) : "v"(ev[6]), "v"(ev[7])); \
    bf16x8 af = __builtin_bit_cast(bf16x8, pk);                               \
    __builtin_amdgcn_s_setprio(1);                                            \
    acc[0] = __builtin_amdgcn_mfma_f32_16x16x32_bf16(                         \
        af, __builtin_bit_cast(bf16x8, bv##S##0), acc[0], 0, 0, 0);           \
    acc[1] = __builtin_amdgcn_mfma_f32_16x16x32_bf16(                         \
        af, __builtin_bit_cast(bf16x8, bv##S##1), acc[1], 0, 0, 0);           \
    acc[2] = __builtin_amdgcn_mfma_f32_16x16x32_bf16(                         \
        af, __builtin_bit_cast(bf16x8, bv##S##2), acc[2], 0, 0, 0);           \
    acc[3] = __builtin_amdgcn_mfma_f32_16x16x32_bf16(                         \
        af, __builtin_bit_cast(bf16x8, bv##S##3), acc[3], 0, 0, 0);           \
    __builtin_amdgcn_s_setprio(0);                                            \
  }

  LOADSTEP(A, 0)
  for (int st = 0; st < 128; st += 2) {
    LOADSTEP(B, st + 1)
    COMP(A)
    LOADSTEP(A, st + 2)   // st=126 -> wraps to 0: dead dup, harmless
    COMP(B)
  }
#undef LOADSTEP
#undef COMP

  // ---- rowsum: combine lkg partials; distribute via shfl (no LDS) ----
  racc += __shfl_xor(racc, 16);
  racc += __shfl_xor(racc, 32);
  // lane (lr, lkg) now holds rowsum(row wr*16 + lr)
  float inv[4];
#pragma unroll
  for (int reg = 0; reg < 4; ++reg) {
    float rsv = __shfl(racc, lkg * 4 + reg);
    inv[reg] = 1.f / (rsv == 0.f ? 1.f : rsv);
  }

  // ---- epilogue: divide + elu + store ----
  const size_t obase =
      ((size_t)(b * 4096 + rowbase + wr * 16 + lkg * 4)) * 256 + ch * 128 + wc * 64;
#pragma unroll
  for (int n = 0; n < 4; ++n) {
#pragma unroll
    for (int reg = 0; reg < 4; ++reg) {
      float v = acc[n][reg] * inv[reg];
      out[obase + (size_t)reg * 256 + 16 * n + lr] =
          v > 0.f ? v : (__expf(v) - 1.f);
    }
  }
}

extern "C" void kernel_launch(void* const* d_in, const int* in_sizes, int n_in,
                              void* d_out, int out_size, void* d_ws, size_t ws_size,
                              hipStream_t stream) {
  const float* h = (const float*)d_in[0];
  const int* adj = (const int*)d_in[1];
  const float* W = (const float*)d_in[2];
  const float* a = (const float*)d_in[3];
  float* out = (float*)d_out;

  u16* WbT   = (u16*)d_ws;                                       // 128 KB
  u16* HhTt  = (u16*)((char*)d_ws + 131072);                     // 8 MB
  float* sb  = (float*)((char*)d_ws + 131072 + 8388608);         // 64 KB
  float* db  = sb + 16384;                                       // 64 KB
  u32* maskg = (u32*)((char*)d_ws + 131072 + 8388608 + 131072);  // 8 MB

  hipLaunchKernelGGL(packw,    dim3(4352), dim3(256), 0, stream, adj, maskg, W, WbT);
  hipLaunchKernelGGL(gemm1,    dim3(256),  dim3(256), 0, stream, h, WbT, a, HhTt, sb, db);
  hipLaunchKernelGGL(gat_main, dim3(512),  dim3(512), 0, stream, maskg, HhTt, sb, db, out);
}